// Round 2
// baseline (357.039 us; speedup 1.0000x reference)
//
#include <hip/hip_runtime.h>

#define NBINS 4
#define BLOCK 256
#define WAVES_PER_BLOCK (BLOCK / 64)
#define NBLOCKS 2048  // 8 blocks/CU -> 32 waves/CU with VGPR<=64

struct WS {
    float sum_d2[NBINS];    // sum of (x-y)^2 summed over 2 comps, per bin
    float sum_ad2[NBINS];   // sum of (|x|-|y|)^2, per bin
    unsigned int cnt[NBINS];
};

__device__ __forceinline__ void accum_point(float x0, float x1, float y0, float y1,
                                            float d,
                                            float (&s_d2)[NBINS], float (&s_ad2)[NBINS],
                                            unsigned int (&s_cnt)[NBINS]) {
    float dx0 = x0 - y0, dx1 = x1 - y1;
    float d2 = dx0 * dx0 + dx1 * dx1;
    float ax = sqrtf(x0 * x0 + x1 * x1);
    float ay = sqrtf(y0 * y0 + y1 * y1);
    float da = ax - ay;
    float ad2 = da * da;
    const float bounds[NBINS + 1] = {0.0f, 0.25f, 0.5f, 0.75f, 1.0f};
#pragma unroll
    for (int b = 0; b < NBINS; ++b) {
        // inclusive on both ends, as in the reference (boundary points count twice)
        if (d >= bounds[b] && d <= bounds[b + 1]) {
            s_d2[b] += d2;
            s_ad2[b] += ad2;
            s_cnt[b] += 1u;
        }
    }
}

__device__ __forceinline__ void accum_group(const float4& xa, const float4& xb,
                                            const float4& ya, const float4& yb,
                                            const float4& dd,
                                            float (&s_d2)[NBINS], float (&s_ad2)[NBINS],
                                            unsigned int (&s_cnt)[NBINS]) {
    accum_point(xa.x, xa.y, ya.x, ya.y, dd.x, s_d2, s_ad2, s_cnt);
    accum_point(xa.z, xa.w, ya.z, ya.w, dd.y, s_d2, s_ad2, s_cnt);
    accum_point(xb.x, xb.y, yb.x, yb.y, dd.z, s_d2, s_ad2, s_cnt);
    accum_point(xb.z, xb.w, yb.z, yb.w, dd.w, s_d2, s_ad2, s_cnt);
}

__global__ __launch_bounds__(BLOCK, 8) void radial_loss_main(
    const float* __restrict__ x, const float* __restrict__ y,
    const float* __restrict__ dist, WS* __restrict__ ws, int n) {
    float s_d2[NBINS] = {0.f, 0.f, 0.f, 0.f};
    float s_ad2[NBINS] = {0.f, 0.f, 0.f, 0.f};
    unsigned int s_cnt[NBINS] = {0u, 0u, 0u, 0u};

    const int tid = blockIdx.x * blockDim.x + threadIdx.x;
    const int stride = gridDim.x * blockDim.x;
    const int n4 = n >> 2;  // 4 points per float4-group

    const float4* __restrict__ x4 = (const float4*)x;  // one float4 = 2 points
    const float4* __restrict__ y4 = (const float4*)y;
    const float4* __restrict__ d4 = (const float4*)dist;

    int i = tid;
    // Unrolled-by-2 main loop: issue all 10 loads before any compute (MLP).
    for (; i + stride < n4; i += 2 * stride) {
        const int j = i + stride;
        float4 xa0 = x4[2 * i];
        float4 xb0 = x4[2 * i + 1];
        float4 ya0 = y4[2 * i];
        float4 yb0 = y4[2 * i + 1];
        float4 dd0 = d4[i];
        float4 xa1 = x4[2 * j];
        float4 xb1 = x4[2 * j + 1];
        float4 ya1 = y4[2 * j];
        float4 yb1 = y4[2 * j + 1];
        float4 dd1 = d4[j];
        accum_group(xa0, xb0, ya0, yb0, dd0, s_d2, s_ad2, s_cnt);
        accum_group(xa1, xb1, ya1, yb1, dd1, s_d2, s_ad2, s_cnt);
    }
    for (; i < n4; i += stride) {
        float4 xa = x4[2 * i];
        float4 xb = x4[2 * i + 1];
        float4 ya = y4[2 * i];
        float4 yb = y4[2 * i + 1];
        float4 dd = d4[i];
        accum_group(xa, xb, ya, yb, dd, s_d2, s_ad2, s_cnt);
    }
    // tail (n not divisible by 4)
    for (int k = (n4 << 2) + tid; k < n; k += stride) {
        accum_point(x[2 * k], x[2 * k + 1], y[2 * k], y[2 * k + 1], dist[k],
                    s_d2, s_ad2, s_cnt);
    }

    // wave-64 shuffle reduction
#pragma unroll
    for (int off = 32; off > 0; off >>= 1) {
#pragma unroll
        for (int b = 0; b < NBINS; ++b) {
            s_d2[b] += __shfl_down(s_d2[b], off);
            s_ad2[b] += __shfl_down(s_ad2[b], off);
            s_cnt[b] += __shfl_down(s_cnt[b], off);
        }
    }

    __shared__ float sm_d2[WAVES_PER_BLOCK][NBINS];
    __shared__ float sm_ad2[WAVES_PER_BLOCK][NBINS];
    __shared__ unsigned int sm_cnt[WAVES_PER_BLOCK][NBINS];
    const int wave = threadIdx.x >> 6;
    const int lane = threadIdx.x & 63;
    if (lane == 0) {
#pragma unroll
        for (int b = 0; b < NBINS; ++b) {
            sm_d2[wave][b] = s_d2[b];
            sm_ad2[wave][b] = s_ad2[b];
            sm_cnt[wave][b] = s_cnt[b];
        }
    }
    __syncthreads();
    if (threadIdx.x < NBINS) {
        const int b = threadIdx.x;
        float td2 = 0.f, tad2 = 0.f;
        unsigned int tc = 0u;
#pragma unroll
        for (int w = 0; w < WAVES_PER_BLOCK; ++w) {
            td2 += sm_d2[w][b];
            tad2 += sm_ad2[w][b];
            tc += sm_cnt[w][b];
        }
        atomicAdd(&ws->sum_d2[b], td2);
        atomicAdd(&ws->sum_ad2[b], tad2);
        atomicAdd(&ws->cnt[b], tc);
    }
}

__global__ void radial_loss_final(const WS* __restrict__ ws, float* __restrict__ out) {
    if (threadIdx.x == 0 && blockIdx.x == 0) {
        float loss = 0.f;
#pragma unroll
        for (int b = 0; b < NBINS; ++b) {
            unsigned int c = ws->cnt[b];
            if (c > 0u) {
                float fc = (float)c;
                loss += ws->sum_d2[b] / (2.0f * fc) + 0.1f * (ws->sum_ad2[b] / fc);
            }
        }
        out[0] = loss;
    }
}

extern "C" void kernel_launch(void* const* d_in, const int* in_sizes, int n_in,
                              void* d_out, int out_size, void* d_ws, size_t ws_size,
                              hipStream_t stream) {
    const float* x = (const float*)d_in[0];
    const float* y = (const float*)d_in[1];
    const float* dist = (const float*)d_in[2];
    float* out = (float*)d_out;
    WS* ws = (WS*)d_ws;
    const int n = in_sizes[2];  // dist element count = N

    hipMemsetAsync(ws, 0, sizeof(WS), stream);
    radial_loss_main<<<NBLOCKS, BLOCK, 0, stream>>>(x, y, dist, ws, n);
    radial_loss_final<<<1, 64, 0, stream>>>(ws, out);
}

// Round 3
// 330.929 us; speedup vs baseline: 1.0789x; 1.0789x over previous
//
#include <hip/hip_runtime.h>

#define NBINS 4
#define BLOCK 256
#define UNROLL 4
#define WAVES_PER_BLOCK (BLOCK / 64)
#define NBLOCKS 2048

struct WS {
    float sum_d2[NBINS];
    float sum_ad2[NBINS];
    unsigned int cnt[NBINS];
};

__device__ __forceinline__ void accum_point(float x0, float x1, float y0, float y1,
                                            float d,
                                            float (&s_d2)[NBINS], float (&s_ad2)[NBINS],
                                            unsigned int (&s_cnt)[NBINS]) {
    float dx0 = x0 - y0, dx1 = x1 - y1;
    float d2 = dx0 * dx0 + dx1 * dx1;
    float ax = sqrtf(x0 * x0 + x1 * x1);
    float ay = sqrtf(y0 * y0 + y1 * y1);
    float da = ax - ay;
    float ad2 = da * da;
    const float bounds[NBINS + 1] = {0.0f, 0.25f, 0.5f, 0.75f, 1.0f};
#pragma unroll
    for (int b = 0; b < NBINS; ++b) {
        // inclusive on both ends, as in the reference (boundary points count twice)
        if (d >= bounds[b] && d <= bounds[b + 1]) {
            s_d2[b] += d2;
            s_ad2[b] += ad2;
            s_cnt[b] += 1u;
        }
    }
}

__global__ __launch_bounds__(BLOCK) void radial_loss_main(
    const float* __restrict__ x, const float* __restrict__ y,
    const float* __restrict__ dist, WS* __restrict__ ws, int n) {
    float s_d2[NBINS] = {0.f, 0.f, 0.f, 0.f};
    float s_ad2[NBINS] = {0.f, 0.f, 0.f, 0.f};
    unsigned int s_cnt[NBINS] = {0u, 0u, 0u, 0u};

    const int n2 = n >> 1;  // index space of float4(x,y) / float2(dist): 2 points each
    const float4* __restrict__ x4 = (const float4*)x;   // x4[t] = points 2t, 2t+1
    const float4* __restrict__ y4 = (const float4*)y;
    const float2* __restrict__ dd2 = (const float2*)dist;

    // Contiguous per-block chunk; lane-contiguous loads (full coalescing).
    const int chunk = (n2 + NBLOCKS - 1) / NBLOCKS;
    const int start = blockIdx.x * chunk;
    const int end = min(start + chunk, n2);

    int i = start + threadIdx.x;
    // Unroll x4: 12 independent loads issued before any compute (MLP).
    for (; i + (UNROLL - 1) * BLOCK < end; i += UNROLL * BLOCK) {
        float4 xv[UNROLL], yv[UNROLL];
        float2 dv[UNROLL];
#pragma unroll
        for (int u = 0; u < UNROLL; ++u) xv[u] = x4[i + u * BLOCK];
#pragma unroll
        for (int u = 0; u < UNROLL; ++u) yv[u] = y4[i + u * BLOCK];
#pragma unroll
        for (int u = 0; u < UNROLL; ++u) dv[u] = dd2[i + u * BLOCK];
#pragma unroll
        for (int u = 0; u < UNROLL; ++u) {
            accum_point(xv[u].x, xv[u].y, yv[u].x, yv[u].y, dv[u].x, s_d2, s_ad2, s_cnt);
            accum_point(xv[u].z, xv[u].w, yv[u].z, yv[u].w, dv[u].y, s_d2, s_ad2, s_cnt);
        }
    }
    for (; i < end; i += BLOCK) {
        float4 xv = x4[i];
        float4 yv = y4[i];
        float2 dv = dd2[i];
        accum_point(xv.x, xv.y, yv.x, yv.y, dv.x, s_d2, s_ad2, s_cnt);
        accum_point(xv.z, xv.w, yv.z, yv.w, dv.y, s_d2, s_ad2, s_cnt);
    }
    // odd-n tail (block 0 only; n is even in practice)
    if (blockIdx.x == 0) {
        for (int p = (n2 << 1) + threadIdx.x; p < n; p += BLOCK) {
            accum_point(x[2 * p], x[2 * p + 1], y[2 * p], y[2 * p + 1], dist[p],
                        s_d2, s_ad2, s_cnt);
        }
    }

    // wave-64 shuffle reduction
#pragma unroll
    for (int off = 32; off > 0; off >>= 1) {
#pragma unroll
        for (int b = 0; b < NBINS; ++b) {
            s_d2[b] += __shfl_down(s_d2[b], off);
            s_ad2[b] += __shfl_down(s_ad2[b], off);
            s_cnt[b] += __shfl_down(s_cnt[b], off);
        }
    }

    __shared__ float sm_d2[WAVES_PER_BLOCK][NBINS];
    __shared__ float sm_ad2[WAVES_PER_BLOCK][NBINS];
    __shared__ unsigned int sm_cnt[WAVES_PER_BLOCK][NBINS];
    const int wave = threadIdx.x >> 6;
    const int lane = threadIdx.x & 63;
    if (lane == 0) {
#pragma unroll
        for (int b = 0; b < NBINS; ++b) {
            sm_d2[wave][b] = s_d2[b];
            sm_ad2[wave][b] = s_ad2[b];
            sm_cnt[wave][b] = s_cnt[b];
        }
    }
    __syncthreads();
    if (threadIdx.x < NBINS) {
        const int b = threadIdx.x;
        float td2 = 0.f, tad2 = 0.f;
        unsigned int tc = 0u;
#pragma unroll
        for (int w = 0; w < WAVES_PER_BLOCK; ++w) {
            td2 += sm_d2[w][b];
            tad2 += sm_ad2[w][b];
            tc += sm_cnt[w][b];
        }
        atomicAdd(&ws->sum_d2[b], td2);
        atomicAdd(&ws->sum_ad2[b], tad2);
        atomicAdd(&ws->cnt[b], tc);
    }
}

__global__ void radial_loss_final(const WS* __restrict__ ws, float* __restrict__ out) {
    if (threadIdx.x == 0 && blockIdx.x == 0) {
        float loss = 0.f;
#pragma unroll
        for (int b = 0; b < NBINS; ++b) {
            unsigned int c = ws->cnt[b];
            if (c > 0u) {
                float fc = (float)c;
                loss += ws->sum_d2[b] / (2.0f * fc) + 0.1f * (ws->sum_ad2[b] / fc);
            }
        }
        out[0] = loss;
    }
}

extern "C" void kernel_launch(void* const* d_in, const int* in_sizes, int n_in,
                              void* d_out, int out_size, void* d_ws, size_t ws_size,
                              hipStream_t stream) {
    const float* x = (const float*)d_in[0];
    const float* y = (const float*)d_in[1];
    const float* dist = (const float*)d_in[2];
    float* out = (float*)d_out;
    WS* ws = (WS*)d_ws;
    const int n = in_sizes[2];  // dist element count = N

    hipMemsetAsync(ws, 0, sizeof(WS), stream);
    radial_loss_main<<<NBLOCKS, BLOCK, 0, stream>>>(x, y, dist, ws, n);
    radial_loss_final<<<1, 64, 0, stream>>>(ws, out);
}